// Round 9
// baseline (231.673 us; speedup 1.0000x reference)
//
#include <hip/hip_runtime.h>
#include <hip/hip_bf16.h>

#define AN 256
#define BN 64
#define DN 768
#define G1N 4
#define G2N 8
#define KI 24            // 768 / 32
#define LPAD 776         // LDS row stride in shorts (768 + 8)
#define GRID 384         // fused grid; co-residency guaranteed (see launch_bounds note)

typedef __attribute__((ext_vector_type(8))) short short8;   // 8 bf16
typedef __attribute__((ext_vector_type(4))) short bf16x4;   // 4 bf16
typedef __attribute__((ext_vector_type(4))) float floatx4;  // MFMA acc

static __device__ __forceinline__ unsigned short f2bf(float f) {
    union { float f; unsigned int u; } v; v.f = f;
    unsigned int r = v.u + 0x7FFF + ((v.u >> 16) & 1);  // RNE
    return (unsigned short)(r >> 16);
}
static __device__ __forceinline__ float bf2f(short s) {
    union { unsigned int u; float f; } v;
    v.u = ((unsigned int)(unsigned short)s) << 16;
    return v.f;
}

// Device-scope grid barrier. ctr zeroed by k_init each launch (no poison
// assumptions). Release: __threadfence() (agent scope -> L2 writeback on
// gfx95x) before arrive; acquire: __threadfence() after observing target.
static __device__ __forceinline__ void grid_barrier(unsigned* ctr, unsigned target) {
    __syncthreads();
    if (threadIdx.x == 0) {
        __threadfence();
        atomicAdd(ctr, 1u);
        while (__hip_atomic_load(ctr, __ATOMIC_RELAXED, __HIP_MEMORY_SCOPE_AGENT) < target)
            __builtin_amdgcn_s_sleep(2);
        __threadfence();
    }
    __syncthreads();
}

__global__ __launch_bounds__(64) void k_init(unsigned* __restrict__ ctr) {
    if (threadIdx.x < 4) ctr[threadIdx.x] = 0u;
}

// ---------------------------------------------------------------------------
// Fused 4-stage kernel, grid = 384 x 256.
//  S0 (bx<256): pack Wh[a]->Whp bf16 (g2-bucketed, l-deinterleaved), s2idx,
//               bcu[c] = b2[g2].Wh_col + bh.
//  S1 (all):    Wcs[g*512+c][d] = W2[g] @ Whp cols   (g=bx/48, d0=(bx%48)*16)
//  S2 (bx<192): Vs[g*512+c][d'] = W1[g] @ Wcs cols; dt==0 also sv=b1.u+bcu
//  S3 (bx<128): out[b,a,l] = pooled[b,:].Vs_col + sv  (g=bx/32, x=bx%32)
// launch_bounds(256,2): VGPR capped so >=2 blocks/CU -> 512 slots >= 384:
// all blocks co-resident, barriers cannot deadlock. LDS 27.9 KB -> 5/CU.
// ---------------------------------------------------------------------------
__global__ __launch_bounds__(256, 2) void k_fused(
    const float* __restrict__ pooled, const float* __restrict__ W1,
    const float* __restrict__ b1, const float* __restrict__ W2,
    const float* __restrict__ b2, const float* __restrict__ Wh,
    const float* __restrict__ bh, const int* __restrict__ g1i,
    const int* __restrict__ g2i,
    unsigned* __restrict__ ctr, float* __restrict__ bcu,
    float* __restrict__ sv, int* __restrict__ s2idx,
    unsigned short* __restrict__ Whp, unsigned short* __restrict__ Wcs,
    unsigned short* __restrict__ Vs, float* __restrict__ out)
{
    __shared__ unsigned short Bs[16 * LPAD];   // 24.8 KB weight slice
    __shared__ int arrA[AN];                   // g2s / g1s
    __shared__ int arrB[AN];                   // lst
    __shared__ int arrC[AN];                   // rpa
    __shared__ int sscalar;

    const int bx = blockIdx.x;
    const int tid = threadIdx.x;
    const int lane = tid & 63, wave = tid >> 6;
    const int nn = lane & 15, quad = lane >> 4;

    // ================= Stage 0: pack Wh =================
    if (bx < 256) {
        const int a = bx;
        arrA[tid] = g2i[tid];
        __syncthreads();
        if (tid == 0) {
            int my = arrA[a], s = 0;
            for (int j = 0; j < a; ++j) s += (arrA[j] == my);
            sscalar = s;
            s2idx[a] = s;
        }
        __syncthreads();
        const int my = arrA[a], s = sscalar;
        const size_t r0 = (size_t)my * 512 + 2 * s;
        const float* wa = Wh + (size_t)a * (DN * 2);
        #pragma unroll
        for (int i = 0; i < 3; ++i) {
            int e = i * 256 + tid;
            float2 v = *(const float2*)(wa + e * 2);
            Whp[r0 * DN + e]       = f2bf(v.x);
            Whp[(r0 + 1) * DN + e] = f2bf(v.y);
        }
        if (wave < 2) {
            const int l = wave;
            const float* b2p = b2 + (size_t)my * DN;
            float sacc = 0.f;
            #pragma unroll
            for (int k = 0; k < 12; ++k) {
                int e = k * 64 + lane;
                sacc += wa[e * 2 + l] * b2p[e];
            }
            #pragma unroll
            for (int off = 1; off < 64; off <<= 1) sacc += __shfl_xor(sacc, off, 64);
            if (lane == 0) bcu[r0 + l] = sacc + bh[a * 2 + l];
        }
    }
    grid_barrier(ctr + 0, GRID);

    // ================= Stage 1: Wcs = W2 @ Whp cols =================
    {
        const int g = bx / 48, d0 = (bx % 48) * 16;
        const int n = __syncthreads_count(g2i[tid] == g);
        const int cols = 2 * n;
        const int nct = (cols + 15) >> 4;
        {
            const int srow = tid >> 4, t16 = tid & 15;
            const float* srcr = W2 + ((size_t)g * DN + d0 + srow) * DN;
            unsigned short* dstr = &Bs[srow * LPAD];
            #pragma unroll
            for (int i = 0; i < 12; ++i) {
                int col4 = (i * 16 + t16) * 4;
                float4 v = *(const float4*)(srcr + col4);
                bf16x4 b;
                b[0] = (short)f2bf(v.x); b[1] = (short)f2bf(v.y);
                b[2] = (short)f2bf(v.z); b[3] = (short)f2bf(v.w);
                *(bf16x4*)(dstr + col4) = b;
            }
        }
        __syncthreads();
        const unsigned short* bsp = &Bs[nn * LPAD + quad * 8];
        for (int ct = wave; ct < nct; ct += 4) {
            const int c = ct * 16 + nn;
            const int cl = (c < cols) ? c : cols - 1;
            const unsigned short* ap = Whp + ((size_t)g * 512 + cl) * DN + quad * 8;
            floatx4 acc = {0, 0, 0, 0};
            #pragma unroll
            for (int kk = 0; kk < KI; ++kk) {
                short8 af = *(const short8*)(ap + kk * 32);
                short8 bf = *(const short8*)(bsp + kk * 32);
                acc = __builtin_amdgcn_mfma_f32_16x16x32_bf16(af, bf, acc, 0, 0, 0);
            }
            #pragma unroll
            for (int r = 0; r < 4; ++r) {
                int cc = ct * 16 + quad * 4 + r;
                if (cc < cols)
                    Wcs[((size_t)g * 512 + cc) * DN + d0 + nn] = f2bf(acc[r]);
            }
        }
    }
    grid_barrier(ctr + 1, GRID);

    // ================= Stage 2: Vs = W1 @ Wcs cols (+sv) =================
    if (bx < 192) {
        const int g = bx / 48, d0 = (bx % 48) * 16;
        arrA[tid] = g1i[tid];
        arrC[tid] = g2i[tid] * 512 + 2 * s2idx[tid];
        __syncthreads();
        int p1 = 0;
        const int m1 = arrA[tid];
        for (int a2 = 0; a2 < tid; ++a2) p1 += (arrA[a2] == m1);
        const int n = __syncthreads_count(m1 == g);
        if (m1 == g) arrB[p1] = tid;
        const int cols = 2 * n;
        const int nct = (cols + 15) >> 4;
        {
            const int srow = tid >> 4, t16 = tid & 15;
            const float* srcr = W1 + ((size_t)g * DN + d0 + srow) * DN;
            unsigned short* dstr = &Bs[srow * LPAD];
            #pragma unroll
            for (int i = 0; i < 12; ++i) {
                int col4 = (i * 16 + t16) * 4;
                float4 v = *(const float4*)(srcr + col4);
                bf16x4 b;
                b[0] = (short)f2bf(v.x); b[1] = (short)f2bf(v.y);
                b[2] = (short)f2bf(v.z); b[3] = (short)f2bf(v.w);
                *(bf16x4*)(dstr + col4) = b;
            }
        }
        __syncthreads();
        const unsigned short* bsp = &Bs[nn * LPAD + quad * 8];
        const bool biasw = ((bx % 48) == 0);
        for (int ct = wave; ct < nct; ct += 4) {
            const int c = ct * 16 + nn;
            const int cl = (c < cols) ? c : cols - 1;
            const int a = arrB[cl >> 1];
            const int rp = arrC[a] + (cl & 1);
            const unsigned short* ap = Wcs + (size_t)rp * DN + quad * 8;
            floatx4 acc = {0, 0, 0, 0};
            float sacc = 0.f;
            #pragma unroll
            for (int kk = 0; kk < KI; ++kk) {
                short8 af = *(const short8*)(ap + kk * 32);
                if (biasw) {
                    const float* b1p = b1 + (size_t)g * DN + kk * 32 + quad * 8;
                    float4 c0v = *(const float4*)(b1p);
                    float4 c1v = *(const float4*)(b1p + 4);
                    sacc += bf2f(af[0]) * c0v.x + bf2f(af[1]) * c0v.y
                          + bf2f(af[2]) * c0v.z + bf2f(af[3]) * c0v.w
                          + bf2f(af[4]) * c1v.x + bf2f(af[5]) * c1v.y
                          + bf2f(af[6]) * c1v.z + bf2f(af[7]) * c1v.w;
                }
                short8 bf = *(const short8*)(bsp + kk * 32);
                acc = __builtin_amdgcn_mfma_f32_16x16x32_bf16(af, bf, acc, 0, 0, 0);
            }
            #pragma unroll
            for (int r = 0; r < 4; ++r) {
                int cc = ct * 16 + quad * 4 + r;
                if (cc < cols)
                    Vs[((size_t)g * 512 + cc) * DN + d0 + nn] = f2bf(acc[r]);
            }
            if (biasw) {
                sacc += __shfl_xor(sacc, 16, 64);
                sacc += __shfl_xor(sacc, 32, 64);
                if (quad == 0 && c < cols)
                    sv[g * 512 + c] = sacc + bcu[rp];
            }
        }
    }
    grid_barrier(ctr + 2, GRID);

    // ================= Stage 3: out = pooled @ Vs cols =================
    if (bx < 128) {
        const int g = bx / 32, x = bx % 32;
        arrA[tid] = g1i[tid];
        __syncthreads();
        int p1 = 0;
        const int m1 = arrA[tid];
        for (int a2 = 0; a2 < tid; ++a2) p1 += (arrA[a2] == m1);
        const int n = __syncthreads_count(m1 == g);
        if (m1 == g) arrB[p1] = tid;
        __syncthreads();
        const int cols = 2 * n;
        const int nt0 = x * 16;
        if (nt0 < cols) {
            const int c = nt0 + nn;
            const bool valid = (c < cols);
            const int cl = valid ? c : cols - 1;
            const int a = arrB[cl >> 1], l = cl & 1;
            const float* ap = pooled + (size_t)(wave * 16 + nn) * DN + quad * 8;
            const unsigned short* bp = Vs + (size_t)(g * 512 + cl) * DN + quad * 8;
            floatx4 acc = {0, 0, 0, 0};
            #pragma unroll
            for (int kk = 0; kk < KI; ++kk) {
                float4 a0 = *(const float4*)(ap + kk * 32);
                float4 a1 = *(const float4*)(ap + kk * 32 + 4);
                short8 af;
                af[0] = (short)f2bf(a0.x); af[1] = (short)f2bf(a0.y);
                af[2] = (short)f2bf(a0.z); af[3] = (short)f2bf(a0.w);
                af[4] = (short)f2bf(a1.x); af[5] = (short)f2bf(a1.y);
                af[6] = (short)f2bf(a1.z); af[7] = (short)f2bf(a1.w);
                short8 bf = *(const short8*)(bp + kk * 32);
                acc = __builtin_amdgcn_mfma_f32_16x16x32_bf16(af, bf, acc, 0, 0, 0);
            }
            if (valid) {
                const float bv = sv[g * 512 + cl];
                #pragma unroll
                for (int r = 0; r < 4; ++r)
                    out[(size_t)(wave * 16 + quad * 4 + r) * (AN * 2) + a * 2 + l] = acc[r] + bv;
            }
        }
    }
}

extern "C" void kernel_launch(void* const* d_in, const int* in_sizes, int n_in,
                              void* d_out, int out_size, void* d_ws, size_t ws_size,
                              hipStream_t stream) {
    const float* pooled = (const float*)d_in[0];
    const float* W1     = (const float*)d_in[1];
    const float* b1     = (const float*)d_in[2];
    const float* W2     = (const float*)d_in[3];
    const float* b2     = (const float*)d_in[4];
    const float* Wh     = (const float*)d_in[5];
    const float* bh     = (const float*)d_in[6];
    const int*   g1i    = (const int*)d_in[7];
    const int*   g2i    = (const int*)d_in[8];
    float* out = (float*)d_out;

    // Workspace carve (~15.8 MB): ctr | bcu | sv | s2idx | Whp | Wcs | Vs
    char* ws = (char*)d_ws;
    unsigned* ctr = (unsigned*)ws;              ws += 16;
    float* bcu   = (float*)ws;                  ws += (size_t)G2N * 512 * 4;
    float* sv    = (float*)ws;                  ws += (size_t)G1N * 512 * 4;
    int*   s2idx = (int*)ws;                    ws += (size_t)AN * 4;
    unsigned short* Whp = (unsigned short*)ws;  ws += (size_t)G2N * 512 * DN * 2;
    unsigned short* Wcs = (unsigned short*)ws;  ws += (size_t)G2N * 512 * DN * 2;
    unsigned short* Vs  = (unsigned short*)ws;  ws += (size_t)G1N * 512 * DN * 2;

    k_init <<<dim3(1),    dim3(64),  0, stream>>>(ctr);
    k_fused<<<dim3(GRID), dim3(256), 0, stream>>>(pooled, W1, b1, W2, b2, Wh, bh,
                                                  g1i, g2i, ctr, bcu, sv, s2idx,
                                                  Whp, Wcs, Vs, out);
}

// Round 10
// 224.709 us; speedup vs baseline: 1.0310x; 1.0310x over previous
//
#include <hip/hip_runtime.h>
#include <hip/hip_bf16.h>

#define AN 256
#define BN 64
#define DN 768
#define G1N 4
#define G2N 8
#define KI 24            // 768 / 32
#define LPAD 776         // LDS row stride in shorts (768 + 8)
#define GRID 384         // fused grid; co-residency guaranteed (see launch_bounds note)

typedef __attribute__((ext_vector_type(8))) short short8;   // 8 bf16
typedef __attribute__((ext_vector_type(4))) short bf16x4;   // 4 bf16
typedef __attribute__((ext_vector_type(4))) float floatx4;  // MFMA acc

static __device__ __forceinline__ unsigned short f2bf(float f) {
    union { float f; unsigned int u; } v; v.f = f;
    unsigned int r = v.u + 0x7FFF + ((v.u >> 16) & 1);  // RNE
    return (unsigned short)(r >> 16);
}
static __device__ __forceinline__ float bf2f(short s) {
    union { unsigned int u; float f; } v;
    v.u = ((unsigned int)(unsigned short)s) << 16;
    return v.f;
}

// Device-scope grid barrier. ctr zeroed by k_init each launch.
// R9 lesson: s_sleep(2) polling floods the LLC slice with ~2 atomic ops/ns
// from 384 spinners, queueing the release atomicAdds behind them (~45 us per
// barrier). Throttle to s_sleep(32) (~0.85 us) after one immediate check:
// offered load drops ~30x; barrier cost ~= arrival spread + <=1 us.
static __device__ __forceinline__ void grid_barrier(unsigned* ctr, unsigned target) {
    __syncthreads();
    if (threadIdx.x == 0) {
        __threadfence();
        atomicAdd(ctr, 1u);
        while (__hip_atomic_load(ctr, __ATOMIC_RELAXED, __HIP_MEMORY_SCOPE_AGENT) < target) {
            __builtin_amdgcn_s_sleep(32);
        }
        __threadfence();
    }
    __syncthreads();
}

__global__ __launch_bounds__(64) void k_init(unsigned* __restrict__ ctr) {
    if (threadIdx.x < 4) ctr[threadIdx.x] = 0u;
}

// ---------------------------------------------------------------------------
// Fused 4-stage kernel, grid = 384 x 256.
//  S0 (bx<256): pack Wh[a]->Whp bf16 (g2-bucketed, l-deinterleaved), s2idx,
//               bcu[c] = b2[g2].Wh_col + bh.
//  S1 (all):    Wcs[g*512+c][d] = W2[g] @ Whp cols   (g=bx/48, d0=(bx%48)*16)
//  S2 (bx<192): Vs[g*512+c][d'] = W1[g] @ Wcs cols; dt==0 also sv=b1.u+bcu
//  S3 (bx<128): out[b,a,l] = pooled[b,:].Vs_col + sv  (g=bx/32, x=bx%32)
// launch_bounds(256,2): VGPR capped so >=2 blocks/CU -> 512 slots >= 384:
// all blocks co-resident, barriers cannot deadlock. LDS 27.9 KB -> 5/CU.
// ---------------------------------------------------------------------------
__global__ __launch_bounds__(256, 2) void k_fused(
    const float* __restrict__ pooled, const float* __restrict__ W1,
    const float* __restrict__ b1, const float* __restrict__ W2,
    const float* __restrict__ b2, const float* __restrict__ Wh,
    const float* __restrict__ bh, const int* __restrict__ g1i,
    const int* __restrict__ g2i,
    unsigned* __restrict__ ctr, float* __restrict__ bcu,
    float* __restrict__ sv, int* __restrict__ s2idx,
    unsigned short* __restrict__ Whp, unsigned short* __restrict__ Wcs,
    unsigned short* __restrict__ Vs, float* __restrict__ out)
{
    __shared__ unsigned short Bs[16 * LPAD];   // 24.8 KB weight slice
    __shared__ int arrA[AN];                   // g2s / g1s
    __shared__ int arrB[AN];                   // lst
    __shared__ int arrC[AN];                   // rpa
    __shared__ int sscalar;

    const int bx = blockIdx.x;
    const int tid = threadIdx.x;
    const int lane = tid & 63, wave = tid >> 6;
    const int nn = lane & 15, quad = lane >> 4;

    // ================= Stage 0: pack Wh =================
    if (bx < 256) {
        const int a = bx;
        arrA[tid] = g2i[tid];
        __syncthreads();
        if (tid == 0) {
            int my = arrA[a], s = 0;
            for (int j = 0; j < a; ++j) s += (arrA[j] == my);
            sscalar = s;
            s2idx[a] = s;
        }
        __syncthreads();
        const int my = arrA[a], s = sscalar;
        const size_t r0 = (size_t)my * 512 + 2 * s;
        const float* wa = Wh + (size_t)a * (DN * 2);
        #pragma unroll
        for (int i = 0; i < 3; ++i) {
            int e = i * 256 + tid;
            float2 v = *(const float2*)(wa + e * 2);
            Whp[r0 * DN + e]       = f2bf(v.x);
            Whp[(r0 + 1) * DN + e] = f2bf(v.y);
        }
        if (wave < 2) {
            const int l = wave;
            const float* b2p = b2 + (size_t)my * DN;
            float sacc = 0.f;
            #pragma unroll
            for (int k = 0; k < 12; ++k) {
                int e = k * 64 + lane;
                sacc += wa[e * 2 + l] * b2p[e];
            }
            #pragma unroll
            for (int off = 1; off < 64; off <<= 1) sacc += __shfl_xor(sacc, off, 64);
            if (lane == 0) bcu[r0 + l] = sacc + bh[a * 2 + l];
        }
    }
    grid_barrier(ctr + 0, GRID);

    // ================= Stage 1: Wcs = W2 @ Whp cols =================
    {
        const int g = bx / 48, d0 = (bx % 48) * 16;
        const int n = __syncthreads_count(g2i[tid] == g);
        const int cols = 2 * n;
        const int nct = (cols + 15) >> 4;
        {
            const int srow = tid >> 4, t16 = tid & 15;
            const float* srcr = W2 + ((size_t)g * DN + d0 + srow) * DN;
            unsigned short* dstr = &Bs[srow * LPAD];
            #pragma unroll
            for (int i = 0; i < 12; ++i) {
                int col4 = (i * 16 + t16) * 4;
                float4 v = *(const float4*)(srcr + col4);
                bf16x4 b;
                b[0] = (short)f2bf(v.x); b[1] = (short)f2bf(v.y);
                b[2] = (short)f2bf(v.z); b[3] = (short)f2bf(v.w);
                *(bf16x4*)(dstr + col4) = b;
            }
        }
        __syncthreads();
        const unsigned short* bsp = &Bs[nn * LPAD + quad * 8];
        for (int ct = wave; ct < nct; ct += 4) {
            const int c = ct * 16 + nn;
            const int cl = (c < cols) ? c : cols - 1;
            const unsigned short* ap = Whp + ((size_t)g * 512 + cl) * DN + quad * 8;
            floatx4 acc = {0, 0, 0, 0};
            #pragma unroll
            for (int kk = 0; kk < KI; ++kk) {
                short8 af = *(const short8*)(ap + kk * 32);
                short8 bf = *(const short8*)(bsp + kk * 32);
                acc = __builtin_amdgcn_mfma_f32_16x16x32_bf16(af, bf, acc, 0, 0, 0);
            }
            #pragma unroll
            for (int r = 0; r < 4; ++r) {
                int cc = ct * 16 + quad * 4 + r;
                if (cc < cols)
                    Wcs[((size_t)g * 512 + cc) * DN + d0 + nn] = f2bf(acc[r]);
            }
        }
    }
    grid_barrier(ctr + 1, GRID);

    // ================= Stage 2: Vs = W1 @ Wcs cols (+sv) =================
    if (bx < 192) {
        const int g = bx / 48, d0 = (bx % 48) * 16;
        arrA[tid] = g1i[tid];
        arrC[tid] = g2i[tid] * 512 + 2 * s2idx[tid];
        __syncthreads();
        int p1 = 0;
        const int m1 = arrA[tid];
        for (int a2 = 0; a2 < tid; ++a2) p1 += (arrA[a2] == m1);
        const int n = __syncthreads_count(m1 == g);
        if (m1 == g) arrB[p1] = tid;
        const int cols = 2 * n;
        const int nct = (cols + 15) >> 4;
        {
            const int srow = tid >> 4, t16 = tid & 15;
            const float* srcr = W1 + ((size_t)g * DN + d0 + srow) * DN;
            unsigned short* dstr = &Bs[srow * LPAD];
            #pragma unroll
            for (int i = 0; i < 12; ++i) {
                int col4 = (i * 16 + t16) * 4;
                float4 v = *(const float4*)(srcr + col4);
                bf16x4 b;
                b[0] = (short)f2bf(v.x); b[1] = (short)f2bf(v.y);
                b[2] = (short)f2bf(v.z); b[3] = (short)f2bf(v.w);
                *(bf16x4*)(dstr + col4) = b;
            }
        }
        __syncthreads();
        const unsigned short* bsp = &Bs[nn * LPAD + quad * 8];
        const bool biasw = ((bx % 48) == 0);
        for (int ct = wave; ct < nct; ct += 4) {
            const int c = ct * 16 + nn;
            const int cl = (c < cols) ? c : cols - 1;
            const int a = arrB[cl >> 1];
            const int rp = arrC[a] + (cl & 1);
            const unsigned short* ap = Wcs + (size_t)rp * DN + quad * 8;
            floatx4 acc = {0, 0, 0, 0};
            float sacc = 0.f;
            #pragma unroll
            for (int kk = 0; kk < KI; ++kk) {
                short8 af = *(const short8*)(ap + kk * 32);
                if (biasw) {
                    const float* b1p = b1 + (size_t)g * DN + kk * 32 + quad * 8;
                    float4 c0v = *(const float4*)(b1p);
                    float4 c1v = *(const float4*)(b1p + 4);
                    sacc += bf2f(af[0]) * c0v.x + bf2f(af[1]) * c0v.y
                          + bf2f(af[2]) * c0v.z + bf2f(af[3]) * c0v.w
                          + bf2f(af[4]) * c1v.x + bf2f(af[5]) * c1v.y
                          + bf2f(af[6]) * c1v.z + bf2f(af[7]) * c1v.w;
                }
                short8 bf = *(const short8*)(bsp + kk * 32);
                acc = __builtin_amdgcn_mfma_f32_16x16x32_bf16(af, bf, acc, 0, 0, 0);
            }
            #pragma unroll
            for (int r = 0; r < 4; ++r) {
                int cc = ct * 16 + quad * 4 + r;
                if (cc < cols)
                    Vs[((size_t)g * 512 + cc) * DN + d0 + nn] = f2bf(acc[r]);
            }
            if (biasw) {
                sacc += __shfl_xor(sacc, 16, 64);
                sacc += __shfl_xor(sacc, 32, 64);
                if (quad == 0 && c < cols)
                    sv[g * 512 + c] = sacc + bcu[rp];
            }
        }
    }
    grid_barrier(ctr + 2, GRID);

    // ================= Stage 3: out = pooled @ Vs cols =================
    if (bx < 128) {
        const int g = bx / 32, x = bx % 32;
        arrA[tid] = g1i[tid];
        __syncthreads();
        int p1 = 0;
        const int m1 = arrA[tid];
        for (int a2 = 0; a2 < tid; ++a2) p1 += (arrA[a2] == m1);
        const int n = __syncthreads_count(m1 == g);
        if (m1 == g) arrB[p1] = tid;
        __syncthreads();
        const int cols = 2 * n;
        const int nt0 = x * 16;
        if (nt0 < cols) {
            const int c = nt0 + nn;
            const bool valid = (c < cols);
            const int cl = valid ? c : cols - 1;
            const int a = arrB[cl >> 1], l = cl & 1;
            const float* ap = pooled + (size_t)(wave * 16 + nn) * DN + quad * 8;
            const unsigned short* bp = Vs + (size_t)(g * 512 + cl) * DN + quad * 8;
            floatx4 acc = {0, 0, 0, 0};
            #pragma unroll
            for (int kk = 0; kk < KI; ++kk) {
                float4 a0 = *(const float4*)(ap + kk * 32);
                float4 a1 = *(const float4*)(ap + kk * 32 + 4);
                short8 af;
                af[0] = (short)f2bf(a0.x); af[1] = (short)f2bf(a0.y);
                af[2] = (short)f2bf(a0.z); af[3] = (short)f2bf(a0.w);
                af[4] = (short)f2bf(a1.x); af[5] = (short)f2bf(a1.y);
                af[6] = (short)f2bf(a1.z); af[7] = (short)f2bf(a1.w);
                short8 bf = *(const short8*)(bp + kk * 32);
                acc = __builtin_amdgcn_mfma_f32_16x16x32_bf16(af, bf, acc, 0, 0, 0);
            }
            if (valid) {
                const float bv = sv[g * 512 + cl];
                #pragma unroll
                for (int r = 0; r < 4; ++r)
                    out[(size_t)(wave * 16 + quad * 4 + r) * (AN * 2) + a * 2 + l] = acc[r] + bv;
            }
        }
    }
}

extern "C" void kernel_launch(void* const* d_in, const int* in_sizes, int n_in,
                              void* d_out, int out_size, void* d_ws, size_t ws_size,
                              hipStream_t stream) {
    const float* pooled = (const float*)d_in[0];
    const float* W1     = (const float*)d_in[1];
    const float* b1     = (const float*)d_in[2];
    const float* W2     = (const float*)d_in[3];
    const float* b2     = (const float*)d_in[4];
    const float* Wh     = (const float*)d_in[5];
    const float* bh     = (const float*)d_in[6];
    const int*   g1i    = (const int*)d_in[7];
    const int*   g2i    = (const int*)d_in[8];
    float* out = (float*)d_out;

    // Workspace carve (~15.8 MB): ctr | bcu | sv | s2idx | Whp | Wcs | Vs
    char* ws = (char*)d_ws;
    unsigned* ctr = (unsigned*)ws;              ws += 16;
    float* bcu   = (float*)ws;                  ws += (size_t)G2N * 512 * 4;
    float* sv    = (float*)ws;                  ws += (size_t)G1N * 512 * 4;
    int*   s2idx = (int*)ws;                    ws += (size_t)AN * 4;
    unsigned short* Whp = (unsigned short*)ws;  ws += (size_t)G2N * 512 * DN * 2;
    unsigned short* Wcs = (unsigned short*)ws;  ws += (size_t)G2N * 512 * DN * 2;
    unsigned short* Vs  = (unsigned short*)ws;  ws += (size_t)G1N * 512 * DN * 2;

    k_init <<<dim3(1),    dim3(64),  0, stream>>>(ctr);
    k_fused<<<dim3(GRID), dim3(256), 0, stream>>>(pooled, W1, b1, W2, b2, Wh, bh,
                                                  g1i, g2i, ctr, bcu, sv, s2idx,
                                                  Whp, Wcs, Vs, out);
}